// Round 4
// baseline (514.007 us; speedup 1.0000x reference)
//
#include <hip/hip_runtime.h>

// FullyAdjacent rewiring: output is [2, G*N*N] int32, flattened.
//   rows half: out[j]        = (j % N^2) / N      (j in [0, half))
//   cols half: out[half + i] = i % N              (i in [0, half))
// N = in_sizes[2] (batch length), half = out_size/2.
//
// Round 3 finding: bench dur_us (501) = harness poison-fill (~346 µs, in the
// timed region, out of our control) + kernel (~155 µs). Kernel at 1 store per
// thread was wave-launch-overhead-bound (524K waves, 1 store each), not
// cache-path-bound (nt vs cached identical). Fix: grid-stride, K stores per
// thread, 64 blocks/CU — amortize wave setup like the 6.2 TB/s memset does.

typedef int v4i __attribute__((ext_vector_type(4)));

#ifndef FA_K
#define FA_K 8   // int4 groups (16B stores) per thread
#endif

__global__ __launch_bounds__(256) void fa_pow2_kernel(
    int* __restrict__ out,
    unsigned n4,        // total int4 groups (n/4)
    unsigned half,      // n/2 in int32 elems, multiple of 4
    int shiftN,         // log2(N)
    int maskN)          // N-1
{
    unsigned stride = gridDim.x * blockDim.x;          // int4 groups per sweep
    unsigned i4 = blockIdx.x * blockDim.x + threadIdx.x;
#pragma unroll
    for (int k = 0; k < FA_K; ++k, i4 += stride) {
        if (i4 < n4) {
            unsigned j = i4 << 2;       // int32 index of this group
            v4i v;
            if (j < half) {
                // rows: (j % N^2)/N == (j >> shiftN) & maskN (pow2 N);
                // constant across the 4-group since 4 | N.
                int r = (int)((j >> shiftN) & (unsigned)maskN);
                v = (v4i){r, r, r, r};
            } else {
                // cols: (j - half) % N; no wrap in-group since 4 | N.
                int c = (int)((j - half) & (unsigned)maskN);
                v = (v4i){c, c + 1, c + 2, c + 3};
            }
            *(v4i*)(out + j) = v;       // plain global_store_dwordx4
        }
    }
}

// Fallback for non-pow2 N or unaligned sizes (not expected for this problem).
__global__ __launch_bounds__(256) void fa_generic_kernel(
    int* __restrict__ out, long long n, long long half, long long N)
{
    long long stride = (long long)gridDim.x * blockDim.x;
    for (long long j = (long long)blockIdx.x * blockDim.x + threadIdx.x;
         j < n; j += stride) {
        long long NN = N * N;
        int val;
        if (j < half) val = (int)((j % NN) / N);
        else          val = (int)((j - half) % N);
        out[j] = val;
    }
}

extern "C" void kernel_launch(void* const* d_in, const int* in_sizes, int n_in,
                              void* d_out, int out_size, void* d_ws, size_t ws_size,
                              hipStream_t stream) {
    (void)d_in; (void)d_ws; (void)ws_size;
    int* out = (int*)d_out;
    long long n = (long long)out_size;
    long long half = n / 2;
    long long N = (n_in >= 3) ? (long long)in_sizes[2] : 4096;  // batch length

    bool pow2 = (N > 0) && ((N & (N - 1)) == 0);
    bool aligned = (n % 4 == 0) && (half % 4 == 0) && (N % 4 == 0);

    if (pow2 && aligned) {
        int shiftN = 0;
        while ((1LL << shiftN) < N) ++shiftN;
        int maskN = (int)(N - 1);
        long long n4 = n >> 2;
        int block = 256;
        long long threads = (n4 + FA_K - 1) / FA_K;
        long long grid = (threads + block - 1) / block;
        fa_pow2_kernel<<<(dim3)(unsigned)grid, block, 0, stream>>>(
            out, (unsigned)n4, (unsigned)half, shiftN, maskN);
    } else {
        int block = 256;
        long long grid = (n + block - 1) / block;
        if (grid > 65535) grid = 65535;
        fa_generic_kernel<<<(dim3)(unsigned)grid, block, 0, stream>>>(
            out, n, half, N);
    }
}